// Round 3
// baseline (601.592 us; speedup 1.0000x reference)
//
#include <hip/hip_runtime.h>
#include <stdint.h>

#define N_ROWS 65536
#define K_CENT 256
#define D_DIM  256
#define GRID_BLOCKS (N_ROWS / 64)   // 1024 = 4/CU * 256 CU, fully resident
#define RED_BLOCKS  64

typedef __attribute__((ext_vector_type(8))) short bf16x8;
typedef __attribute__((ext_vector_type(4))) float f32x4;

__device__ __forceinline__ float bf2f(unsigned short u) {
    union { unsigned int i; float f; } v;
    v.i = ((unsigned int)u) << 16;
    return v.f;
}

__device__ __forceinline__ unsigned short f2bf(float f) {
    union { float f; unsigned int i; } v;
    v.f = f;
    unsigned int r = (v.i + 0x7FFFu + ((v.i >> 16) & 1u)) >> 16;
    return (unsigned short)r;
}

__device__ __forceinline__ unsigned int agent_load(const unsigned int* p) {
    return __hip_atomic_load(p, __ATOMIC_ACQUIRE, __HIP_MEMORY_SCOPE_AGENT);
}

// ---------- c2[k] = sum_d round_bf16(cent[k][d])^2; emit LINEAR bf16 copy ----
__global__ void c2_kernel(const float* __restrict__ cent,
                          float* __restrict__ c2,
                          unsigned short* __restrict__ cent_bf) {
    int row  = blockIdx.x;
    int lane = threadIdx.x; // 64 threads
    const float4 v = *(const float4*)(cent + (size_t)row * D_DIM + lane * 4);
    unsigned short b0 = f2bf(v.x), b1 = f2bf(v.y), b2 = f2bf(v.z), b3 = f2bf(v.w);
    ushort4 bv; bv.x = b0; bv.y = b1; bv.z = b2; bv.w = b3;
    *(ushort4*)(cent_bf + (size_t)row * D_DIM + lane * 4) = bv;
    float f0 = bf2f(b0), f1 = bf2f(b1), f2 = bf2f(b2), f3 = bf2f(b3);
    float s = f0 * f0 + f1 * f1 + f2 * f2 + f3 * f3;
    #pragma unroll
    for (int off = 32; off >= 1; off >>= 1) s += __shfl_xor(s, off, 64);
    if (lane == 0) c2[row] = s;
}

// ---------- fused: pass1 + colsum + pass2, q held in registers across a ------
// SOFTWARE grid barrier (graph-capture-legal, unlike hipLaunchCooperativeKernel).
// Residency: 1024 blocks = 4/CU * 256 CU guaranteed by launch_bounds(256,4)
// (128-VGPR cap) + 16 KB LDS (10/CU worth) + 16 waves/CU <= 32. No deadlock.
__global__ __launch_bounds__(256, 4) void fused_kernel(
        const float* __restrict__ z,
        const unsigned short* __restrict__ cent_bf,
        const float* __restrict__ c2,
        float* __restrict__ partials,
        float* __restrict__ s_col,
        unsigned int* __restrict__ counters,
        float* __restrict__ q_out,
        float* __restrict__ p_out) {
    // Fragment-major: 16B unit F = ks*128 + t*64 + m15*4 + quad
    // (ks = K-step 0..7, t = col-tile 0..1 within 32-row chunk).
    __shared__ __align__(16) unsigned short bstage[32 * D_DIM]; // 16 KB total

    const int tid  = threadIdx.x;
    const int wave = tid >> 6;
    const int lane = tid & 63;
    const int m15  = lane & 15;   // A row within tile / C col within tile
    const int quad = lane >> 4;   // 0..3
    const int row0 = blockIdx.x * 64 + wave * 16;

    // ---- A fragments: all 16 float4 loads issued back-to-back ----
    const float* za = z + (size_t)(row0 + m15) * D_DIM + quad * 8;
    float4 a[16];
    #pragma unroll
    for (int i = 0; i < 8; ++i) {
        a[2 * i]     = *(const float4*)(za + i * 32);
        a[2 * i + 1] = *(const float4*)(za + i * 32 + 4);
    }
    bf16x8 afrag[8];
    float z2p = 0.0f;
    #pragma unroll
    for (int ks = 0; ks < 8; ++ks) {
        const float av[8] = {a[2*ks].x, a[2*ks].y, a[2*ks].z, a[2*ks].w,
                             a[2*ks+1].x, a[2*ks+1].y, a[2*ks+1].z, a[2*ks+1].w};
        #pragma unroll
        for (int j = 0; j < 8; ++j) {
            unsigned short ub = f2bf(av[j]);
            afrag[ks][j] = (short)ub;
            float f = bf2f(ub);
            z2p += f * f;
        }
    }
    z2p += __shfl_xor(z2p, 16, 64);
    z2p += __shfl_xor(z2p, 32, 64);
    float z2r[4];
    #pragma unroll
    for (int r = 0; r < 4; ++r) z2r[r] = __shfl(z2p, quad * 4 + r, 64);

    f32x4 acc[16];
    #pragma unroll
    for (int t = 0; t < 16; ++t) acc[t] = (f32x4){0.f, 0.f, 0.f, 0.f};

    // ---- 8 chunks of 32 centroids; fragment-major staging ----
    #pragma unroll
    for (int c = 0; c < 8; ++c) {
        const unsigned short* src = cent_bf + (size_t)c * 32 * D_DIM;
        bf16x8 st[4];
        #pragma unroll
        for (int i = 0; i < 4; ++i) {
            int F  = i * 256 + tid;                       // dst 16B unit
            int qd = F & 3, mm = (F >> 2) & 15, tt = (F >> 6) & 1, kk = F >> 7;
            int s16 = tt * 512 + mm * 32 + kk * 4 + qd;   // src 16B unit
            st[i] = *(const bf16x8*)&src[s16 * 8];
        }
        #pragma unroll
        for (int i = 0; i < 4; ++i) {
            int F = i * 256 + tid;
            *(bf16x8*)&bstage[F * 8] = st[i];
        }
        __syncthreads();
        #pragma unroll
        for (int ks = 0; ks < 8; ++ks) {
            #pragma unroll
            for (int t = 0; t < 2; ++t) {
                bf16x8 bfrag = *(const bf16x8*)&bstage[(ks * 128 + t * 64 + m15 * 4 + quad) * 8];
                acc[c * 2 + t] = __builtin_amdgcn_mfma_f32_16x16x32_bf16(
                    afrag[ks], bfrag, acc[c * 2 + t], 0, 0, 0);
            }
        }
        __syncthreads();
    }

    // ---- epilogue: q = rownorm(1/(1+sse)); KEEP q in acc for phase C ----
    float rowsum[4] = {0.f, 0.f, 0.f, 0.f};
    #pragma unroll
    for (int t = 0; t < 16; ++t) {
        float c2v = c2[t * 16 + m15];
        #pragma unroll
        for (int r = 0; r < 4; ++r) {
            float sse = z2r[r] + c2v - 2.0f * acc[t][r];
            sse = fmaxf(sse, 0.0f);
            float u = 1.0f / (1.0f + sse);
            acc[t][r] = u;
            rowsum[r] += u;
        }
    }
    #pragma unroll
    for (int r = 0; r < 4; ++r) {
        float v = rowsum[r];
        v += __shfl_xor(v, 1, 64);
        v += __shfl_xor(v, 2, 64);
        v += __shfl_xor(v, 4, 64);
        v += __shfl_xor(v, 8, 64);
        rowsum[r] = 1.0f / v;
    }

    float colp[16];
    #pragma unroll
    for (int t = 0; t < 16; ++t) {
        float cp = 0.0f;
        #pragma unroll
        for (int r = 0; r < 4; ++r) {
            float qv = acc[t][r] * rowsum[r];
            acc[t][r] = qv;   // retain q in registers across grid barrier
            cp += qv;
            q_out[(size_t)(row0 + quad * 4 + r) * K_CENT + t * 16 + m15] = qv;
        }
        cp += __shfl_xor(cp, 16, 64);
        cp += __shfl_xor(cp, 32, 64);
        colp[t] = cp;
    }
    // reuse bstage as col_lds (4 waves x 256 floats = 4 KB <= 16 KB)
    float* col_lds = (float*)bstage;
    if (quad == 0) {
        #pragma unroll
        for (int t = 0; t < 16; ++t) col_lds[wave * K_CENT + t * 16 + lane] = colp[t];
    }
    __syncthreads();
    float sp = col_lds[tid] + col_lds[K_CENT + tid] +
               col_lds[2 * K_CENT + tid] + col_lds[3 * K_CENT + tid];
    partials[(size_t)blockIdx.x * K_CENT + tid] = sp;   // coalesced, NO atomics

    // ---- software grid barrier 1: all partials written ----
    __threadfence();            // device-scope release of this thread's stores
    __syncthreads();            // whole block's fences done
    if (tid == 0) atomicAdd(&counters[0], 1u);

    // ---- reducer blocks: colsum of partials -> s_col ----
    if (blockIdx.x < RED_BLOCKS) {
        if (tid == 0) {
            while (agent_load(&counters[0]) < GRID_BLOCKS)
                __builtin_amdgcn_s_sleep(2);
        }
        __syncthreads();
        __threadfence();        // acquire: invalidate caches before reading
        const float* base = partials + (size_t)blockIdx.x * 16 * K_CENT + tid;
        float s = 0.0f;
        #pragma unroll
        for (int h = 0; h < 16; ++h) s += base[h * K_CENT];
        atomicAdd(&s_col[tid], s);
        __threadfence();        // order s_col atomics before counter bump
        __syncthreads();
        if (tid == 0) atomicAdd(&counters[1], 1u);
    }

    // ---- software grid barrier 2: s_col complete ----
    if (tid == 0) {
        while (agent_load(&counters[1]) < RED_BLOCKS)
            __builtin_amdgcn_s_sleep(2);
    }
    __syncthreads();
    __threadfence();            // acquire before reading s_col

    // ---- phase C: p = rownorm(q^2 / s_col), q still in registers ----
    float rs2[4] = {0.f, 0.f, 0.f, 0.f};
    #pragma unroll
    for (int t = 0; t < 16; ++t) {
        float inv_s = 1.0f / s_col[t * 16 + m15];
        #pragma unroll
        for (int r = 0; r < 4; ++r) {
            float sf = acc[t][r] * acc[t][r] * inv_s;
            acc[t][r] = sf;
            rs2[r] += sf;
        }
    }
    #pragma unroll
    for (int r = 0; r < 4; ++r) {
        float v = rs2[r];
        v += __shfl_xor(v, 1, 64);
        v += __shfl_xor(v, 2, 64);
        v += __shfl_xor(v, 4, 64);
        v += __shfl_xor(v, 8, 64);
        rs2[r] = 1.0f / v;
    }
    #pragma unroll
    for (int t = 0; t < 16; ++t) {
        #pragma unroll
        for (int r = 0; r < 4; ++r) {
            p_out[(size_t)(row0 + quad * 4 + r) * K_CENT + t * 16 + m15] =
                acc[t][r] * rs2[r];
        }
    }
}

extern "C" void kernel_launch(void* const* d_in, const int* in_sizes, int n_in,
                              void* d_out, int out_size, void* d_ws, size_t ws_size,
                              hipStream_t stream) {
    const float* z    = (const float*)d_in[0];
    const float* cent = (const float*)d_in[1];
    float* p_out = (float*)d_out;
    float* q_out = p_out + (size_t)N_ROWS * K_CENT;

    float* c2             = (float*)d_ws;
    float* s_col          = c2 + K_CENT;
    unsigned int* counters = (unsigned int*)(s_col + K_CENT);  // 4 uints
    unsigned short* cent_bf = (unsigned short*)(counters + 4);
    float* partials       = (float*)(cent_bf + K_CENT * D_DIM); // 1 MB

    // zero s_col + counters each replay (captured into the graph)
    hipMemsetAsync(s_col, 0, K_CENT * sizeof(float) + 4 * sizeof(unsigned int),
                   stream);
    c2_kernel<<<K_CENT, 64, 0, stream>>>(cent, c2, cent_bf);
    fused_kernel<<<GRID_BLOCKS, 256, 0, stream>>>(
        z, cent_bf, c2, partials, s_col, counters, q_out, p_out);
}

// Round 4
// 281.795 us; speedup vs baseline: 2.1349x; 2.1349x over previous
//
#include <hip/hip_runtime.h>
#include <stdint.h>

#define N_ROWS 65536
#define K_CENT 256
#define D_DIM  256
#define GRID_BLOCKS (N_ROWS / 64)   // 1024 = 4/CU * 256 CU, fully resident

typedef __attribute__((ext_vector_type(8))) short bf16x8;
typedef __attribute__((ext_vector_type(4))) float f32x4;

__device__ __forceinline__ float bf2f(unsigned short u) {
    union { unsigned int i; float f; } v;
    v.i = ((unsigned int)u) << 16;
    return v.f;
}

__device__ __forceinline__ unsigned short f2bf(float f) {
    union { float f; unsigned int i; } v;
    v.f = f;
    unsigned int r = (v.i + 0x7FFFu + ((v.i >> 16) & 1u)) >> 16;
    return (unsigned short)r;
}

// relaxed agent-scope load: sc1 cache-bypassing read, NO whole-L2 invalidate
// (acquire loads invalidate the XCD L2 every iteration -- that was round 3's
// 340 us stall).
__device__ __forceinline__ unsigned int agent_load_relaxed(const unsigned int* p) {
    return __hip_atomic_load(p, __ATOMIC_RELAXED, __HIP_MEMORY_SCOPE_AGENT);
}

// ---------- c2[k] = sum_d round_bf16(cent[k][d])^2; emit LINEAR bf16 copy ----
__global__ void c2_kernel(const float* __restrict__ cent,
                          float* __restrict__ c2,
                          unsigned short* __restrict__ cent_bf) {
    int row  = blockIdx.x;
    int lane = threadIdx.x; // 64 threads
    const float4 v = *(const float4*)(cent + (size_t)row * D_DIM + lane * 4);
    unsigned short b0 = f2bf(v.x), b1 = f2bf(v.y), b2 = f2bf(v.z), b3 = f2bf(v.w);
    ushort4 bv; bv.x = b0; bv.y = b1; bv.z = b2; bv.w = b3;
    *(ushort4*)(cent_bf + (size_t)row * D_DIM + lane * 4) = bv;
    float f0 = bf2f(b0), f1 = bf2f(b1), f2 = bf2f(b2), f3 = bf2f(b3);
    float s = f0 * f0 + f1 * f1 + f2 * f2 + f3 * f3;
    #pragma unroll
    for (int off = 32; off >= 1; off >>= 1) s += __shfl_xor(s, off, 64);
    if (lane == 0) c2[row] = s;
}

// ---------- fused: pass1 + colsum + pass2, q held in registers ----------
// Fence-free grid sync: col partials published via RETURNING global f32
// atomics (execute AT the Infinity Cache -> cross-XCD visible, no wbl2);
// one arrival counter; relaxed sc1 spin loads. Residency: 1024 blocks =
// 4/CU * 256 CU guaranteed by launch_bounds(256,4) + 16 KB LDS.
__global__ __launch_bounds__(256, 4) void fused_kernel(
        const float* __restrict__ z,
        const unsigned short* __restrict__ cent_bf,
        const float* __restrict__ c2,
        float* __restrict__ s_col,
        unsigned int* __restrict__ counters,
        float* __restrict__ q_out,
        float* __restrict__ p_out) {
    // Fragment-major: 16B unit F = ks*128 + t*64 + m15*4 + quad
    __shared__ __align__(16) unsigned short bstage[32 * D_DIM]; // 16 KB total

    const int tid  = threadIdx.x;
    const int wave = tid >> 6;
    const int lane = tid & 63;
    const int m15  = lane & 15;   // A row within tile / C col within tile
    const int quad = lane >> 4;   // 0..3
    const int row0 = blockIdx.x * 64 + wave * 16;

    // ---- A fragments: all 16 float4 loads issued back-to-back ----
    const float* za = z + (size_t)(row0 + m15) * D_DIM + quad * 8;
    float4 a[16];
    #pragma unroll
    for (int i = 0; i < 8; ++i) {
        a[2 * i]     = *(const float4*)(za + i * 32);
        a[2 * i + 1] = *(const float4*)(za + i * 32 + 4);
    }
    bf16x8 afrag[8];
    float z2p = 0.0f;
    #pragma unroll
    for (int ks = 0; ks < 8; ++ks) {
        const float av[8] = {a[2*ks].x, a[2*ks].y, a[2*ks].z, a[2*ks].w,
                             a[2*ks+1].x, a[2*ks+1].y, a[2*ks+1].z, a[2*ks+1].w};
        #pragma unroll
        for (int j = 0; j < 8; ++j) {
            unsigned short ub = f2bf(av[j]);
            afrag[ks][j] = (short)ub;
            float f = bf2f(ub);
            z2p += f * f;
        }
    }
    z2p += __shfl_xor(z2p, 16, 64);
    z2p += __shfl_xor(z2p, 32, 64);
    float z2r[4];
    #pragma unroll
    for (int r = 0; r < 4; ++r) z2r[r] = __shfl(z2p, quad * 4 + r, 64);

    f32x4 acc[16];
    #pragma unroll
    for (int t = 0; t < 16; ++t) acc[t] = (f32x4){0.f, 0.f, 0.f, 0.f};

    // ---- 8 chunks of 32 centroids; fragment-major staging ----
    #pragma unroll
    for (int c = 0; c < 8; ++c) {
        const unsigned short* src = cent_bf + (size_t)c * 32 * D_DIM;
        bf16x8 st[4];
        #pragma unroll
        for (int i = 0; i < 4; ++i) {
            int F  = i * 256 + tid;                       // dst 16B unit
            int qd = F & 3, mm = (F >> 2) & 15, tt = (F >> 6) & 1, kk = F >> 7;
            int s16 = tt * 512 + mm * 32 + kk * 4 + qd;   // src 16B unit
            st[i] = *(const bf16x8*)&src[s16 * 8];
        }
        #pragma unroll
        for (int i = 0; i < 4; ++i) {
            int F = i * 256 + tid;
            *(bf16x8*)&bstage[F * 8] = st[i];
        }
        __syncthreads();
        #pragma unroll
        for (int ks = 0; ks < 8; ++ks) {
            #pragma unroll
            for (int t = 0; t < 2; ++t) {
                bf16x8 bfrag = *(const bf16x8*)&bstage[(ks * 128 + t * 64 + m15 * 4 + quad) * 8];
                acc[c * 2 + t] = __builtin_amdgcn_mfma_f32_16x16x32_bf16(
                    afrag[ks], bfrag, acc[c * 2 + t], 0, 0, 0);
            }
        }
        __syncthreads();
    }

    // ---- epilogue: q = rownorm(1/(1+sse)); KEEP q in acc for phase C ----
    float rowsum[4] = {0.f, 0.f, 0.f, 0.f};
    #pragma unroll
    for (int t = 0; t < 16; ++t) {
        float c2v = c2[t * 16 + m15];
        #pragma unroll
        for (int r = 0; r < 4; ++r) {
            float sse = z2r[r] + c2v - 2.0f * acc[t][r];
            sse = fmaxf(sse, 0.0f);
            float u = 1.0f / (1.0f + sse);
            acc[t][r] = u;
            rowsum[r] += u;
        }
    }
    #pragma unroll
    for (int r = 0; r < 4; ++r) {
        float v = rowsum[r];
        v += __shfl_xor(v, 1, 64);
        v += __shfl_xor(v, 2, 64);
        v += __shfl_xor(v, 4, 64);
        v += __shfl_xor(v, 8, 64);
        rowsum[r] = 1.0f / v;
    }

    float colp[16];
    #pragma unroll
    for (int t = 0; t < 16; ++t) {
        float cp = 0.0f;
        #pragma unroll
        for (int r = 0; r < 4; ++r) {
            float qv = acc[t][r] * rowsum[r];
            acc[t][r] = qv;   // retain q in registers across grid barrier
            cp += qv;
            q_out[(size_t)(row0 + quad * 4 + r) * K_CENT + t * 16 + m15] = qv;
        }
        cp += __shfl_xor(cp, 16, 64);
        cp += __shfl_xor(cp, 32, 64);
        colp[t] = cp;
    }
    // reuse bstage as col_lds (4 waves x 256 floats = 4 KB <= 16 KB)
    float* col_lds = (float*)bstage;
    if (quad == 0) {
        #pragma unroll
        for (int t = 0; t < 16; ++t) col_lds[wave * K_CENT + t * 16 + lane] = colp[t];
    }
    __syncthreads();
    float sp = col_lds[tid] + col_lds[K_CENT + tid] +
               col_lds[2 * K_CENT + tid] + col_lds[3 * K_CENT + tid];

    // Publish column sums via RETURNING atomic (vmcnt retires only when the
    // RMW has executed at the Infinity Cache -> the implicit vmcnt(0) before
    // the next __syncthreads orders ALL threads' adds before the arrival bump).
    float old = atomicAdd(&s_col[tid], sp);
    asm volatile("" :: "v"(old));   // keep the returning form live

    __syncthreads();

    // ---- fence-free grid barrier ----
    if (tid == 0) {
        __hip_atomic_fetch_add(&counters[0], 1u, __ATOMIC_RELAXED,
                               __HIP_MEMORY_SCOPE_AGENT);
        while (agent_load_relaxed(&counters[0]) < GRID_BLOCKS)
            __builtin_amdgcn_s_sleep(8);
    }
    __syncthreads();

    // ---- phase C: p = rownorm(q^2 / s_col), q still in registers ----
    // s_col lines were never cached by this XCD this dispatch (writes were
    // cache-bypassing atomics) -> plain loads fetch fresh values from IC.
    float rs2[4] = {0.f, 0.f, 0.f, 0.f};
    #pragma unroll
    for (int t = 0; t < 16; ++t) {
        float inv_s = 1.0f / s_col[t * 16 + m15];
        #pragma unroll
        for (int r = 0; r < 4; ++r) {
            float sf = acc[t][r] * acc[t][r] * inv_s;
            acc[t][r] = sf;
            rs2[r] += sf;
        }
    }
    #pragma unroll
    for (int r = 0; r < 4; ++r) {
        float v = rs2[r];
        v += __shfl_xor(v, 1, 64);
        v += __shfl_xor(v, 2, 64);
        v += __shfl_xor(v, 4, 64);
        v += __shfl_xor(v, 8, 64);
        rs2[r] = 1.0f / v;
    }
    #pragma unroll
    for (int t = 0; t < 16; ++t) {
        #pragma unroll
        for (int r = 0; r < 4; ++r) {
            p_out[(size_t)(row0 + quad * 4 + r) * K_CENT + t * 16 + m15] =
                acc[t][r] * rs2[r];
        }
    }
}

extern "C" void kernel_launch(void* const* d_in, const int* in_sizes, int n_in,
                              void* d_out, int out_size, void* d_ws, size_t ws_size,
                              hipStream_t stream) {
    const float* z    = (const float*)d_in[0];
    const float* cent = (const float*)d_in[1];
    float* p_out = (float*)d_out;
    float* q_out = p_out + (size_t)N_ROWS * K_CENT;

    float* c2              = (float*)d_ws;
    float* s_col           = c2 + K_CENT;
    unsigned int* counters = (unsigned int*)(s_col + K_CENT);  // 4 uints
    unsigned short* cent_bf = (unsigned short*)(counters + 4);

    // zero s_col + counters each replay (captured into the graph)
    hipMemsetAsync(s_col, 0, K_CENT * sizeof(float) + 4 * sizeof(unsigned int),
                   stream);
    c2_kernel<<<K_CENT, 64, 0, stream>>>(cent, c2, cent_bf);
    fused_kernel<<<GRID_BLOCKS, 256, 0, stream>>>(
        z, cent_bf, c2, s_col, counters, q_out, p_out);
}